// Round 6
// baseline (215.479 us; speedup 1.0000x reference)
//
#include <hip/hip_runtime.h>
#include <math.h>

#define N_ 2048
#define R_ 64
#define D_ 64
#define K_ 512
#define M_ (N_*R_)      // 131072 rows
#define BM 128          // rows per argmin block (= 2 batch entries)
#define TAU 0.05f       // gap threshold (score units); approx err << TAU/2
#define CHK 0.02f       // winner exact-vs-approx verification threshold

// ws float offsets / byte layout:
// [0] vq acc | [16..527] wn | [1024..5119] gram | byte 32768: whi (64KB) | byte 98304: wlo (64KB)
#define WN_OFF   16
#define GRAM_OFF 1024
#define WBF_BYTE 32768
#define WS_NEED  163840

typedef __attribute__((ext_vector_type(8))) short s16x8;
typedef __attribute__((ext_vector_type(4))) float f32x4;

static __device__ __forceinline__ unsigned short f2bf(float f) {
    unsigned u = __float_as_uint(f);
    u += 0x7FFFu + ((u >> 16) & 1u);
    return (unsigned short)(u >> 16);
}
static __device__ __forceinline__ float bf2f(unsigned short h) {
    return __uint_as_float(((unsigned)h) << 16);
}

// ---------------- k_pre: gram (b<64) | wn + zero acc (b 64-65) | W bf16-split UNswizzled (b 66-67)
__global__ void k_pre(const float* __restrict__ w, float* __restrict__ ws, int pre) {
    const int b = blockIdx.x, t = threadIdx.x;
    if (b < 64) {
        __shared__ float red[4][64];
        const int i = b, j = t & 63, kg = t >> 6;
        float s = 0.f;
        for (int k = kg * 128; k < kg * 128 + 128; ++k)
            s = fmaf(w[k * 64 + i], w[k * 64 + j], s);
        red[kg][j] = s;
        __syncthreads();
        if (t < 64)
            ws[GRAM_OFF + i * 64 + t] = red[0][t] + red[1][t] + red[2][t] + red[3][t];
    } else if (b < 66) {
        const int code = (b - 64) * 256 + t;
        const float4* wr = (const float4*)(w + code * 64);
        float s = 0.f;
#pragma unroll
        for (int i = 0; i < 16; ++i) {
            float4 v = wr[i];
            s += v.x * v.x + v.y * v.y + v.z * v.z + v.w * v.w;
        }
        ws[WN_OFF + code] = s;
        if (b == 64 && t == 0) ws[0] = 0.f;
    } else {
        if (!pre) return;
        const int code = (b - 66) * 256 + t;   // 512 codes
        char* whi = (char*)ws + WBF_BYTE;
        char* wlo = whi + 65536;
        for (int kg = 0; kg < 8; ++kg) {
            float4 v0 = *(const float4*)(w + code * 64 + kg * 8);
            float4 v1 = *(const float4*)(w + code * 64 + kg * 8 + 4);
            const float vv[8] = {v0.x, v0.y, v0.z, v0.w, v1.x, v1.y, v1.z, v1.w};
            s16x8 ph, pl;
#pragma unroll
            for (int j = 0; j < 8; ++j) {
                const unsigned short hb = f2bf(vv[j]);
                ph[j] = (short)hb;
                pl[j] = (short)f2bf(vv[j] - bf2f(hb));
            }
            const int off = code * 128 + kg * 16;   // linear: fragment-contiguous
            *(s16x8*)(whi + off) = ph;
            *(s16x8*)(wlo + off) = pl;
        }
    }
}

// ---------------- k_argmin: barrier-free K-loop, fragments direct from global
template<bool PRE>
__global__ __launch_bounds__(256, 4) void k_argmin(
    const float* __restrict__ x, const float* __restrict__ w,
    float* __restrict__ ws, float* __restrict__ out)
{
    __shared__ float sb1[BM];
    __shared__ float sb2[BM];
    __shared__ int   ridx[BM];
    __shared__ int   ulist[BM];
    __shared__ int   nunc;
    __shared__ float red[2048];            // 8 KB epilogue scratch

    const int t = threadIdx.x;
    const int l = t & 63, wid = t >> 6;
    const int g = l >> 4, lr = l & 15;
    const long base = (long)blockIdx.x * BM;
    const float* wn_g = ws + WN_OFF;
    const char* whi = (const char*)ws + WBF_BYTE;
    const char* wlo = whi + 65536;

    if (t == 0) nunc = 0;

    // ---- A fragments straight from global x, split to bf16 hi/lo in registers.
    // row = lane%16 within tile, k = 8*(lane/16)+e; k-slice s covers k = 32s..32s+31.
    s16x8 ah[2][2], al[2][2];
#pragma unroll
    for (int mt = 0; mt < 2; ++mt) {
        const int row = wid * 32 + mt * 16 + lr;
#pragma unroll
        for (int s = 0; s < 2; ++s) {
            const float* src = x + (base + row) * 64 + (s * 4 + g) * 8;
            const float4 v0 = *(const float4*)src;
            const float4 v1 = *(const float4*)(src + 4);
            const float vv[8] = {v0.x, v0.y, v0.z, v0.w, v1.x, v1.y, v1.z, v1.w};
            s16x8 ph, pl;
#pragma unroll
            for (int j = 0; j < 8; ++j) {
                const unsigned short hb = f2bf(vv[j]);
                ph[j] = (short)hb;
                pl[j] = (short)f2bf(vv[j] - bf2f(hb));
            }
            ah[mt][s] = ph; al[mt][s] = pl;
        }
    }

    float b1[2][4], b2[2][4]; int i1[2][4];
#pragma unroll
    for (int mt = 0; mt < 2; ++mt)
#pragma unroll
        for (int j = 0; j < 4; ++j) { b1[mt][j] = 3.4e38f; b2[mt][j] = 3.4e38f; i1[mt][j] = 0; }

    for (int c = 0; c < 8; ++c) {
        const int cbase = c * 64;
        f32x4 acc[2][4];
        const f32x4 z = {0.f, 0.f, 0.f, 0.f};
#pragma unroll
        for (int mt = 0; mt < 2; ++mt)
#pragma unroll
            for (int nt = 0; nt < 4; ++nt) acc[mt][nt] = z;

#pragma unroll
        for (int s = 0; s < 2; ++s) {
            s16x8 bh[4], bl[4];
#pragma unroll
            for (int nt = 0; nt < 4; ++nt) {   // B: col = lane%16, k = 8*(lane/16)+e
                const int crow = cbase + nt * 16 + lr;
                if constexpr (PRE) {
                    const int off = crow * 128 + (s * 4 + g) * 16;
                    bh[nt] = *(const s16x8*)(whi + off);
                    bl[nt] = *(const s16x8*)(wlo + off);
                } else {
                    const float* src = w + (long)crow * 64 + (s * 4 + g) * 8;
                    const float4 v0 = *(const float4*)src;
                    const float4 v1 = *(const float4*)(src + 4);
                    const float vv[8] = {v0.x, v0.y, v0.z, v0.w, v1.x, v1.y, v1.z, v1.w};
                    s16x8 ph, pl;
#pragma unroll
                    for (int j = 0; j < 8; ++j) {
                        const unsigned short hb = f2bf(vv[j]);
                        ph[j] = (short)hb;
                        pl[j] = (short)f2bf(vv[j] - bf2f(hb));
                    }
                    bh[nt] = ph; bl[nt] = pl;
                }
            }
#pragma unroll
            for (int nt = 0; nt < 4; ++nt)
#pragma unroll
                for (int mt = 0; mt < 2; ++mt) {
                    acc[mt][nt] = __builtin_amdgcn_mfma_f32_16x16x32_bf16(ah[mt][s], bh[nt], acc[mt][nt], 0, 0, 0);
                    acc[mt][nt] = __builtin_amdgcn_mfma_f32_16x16x32_bf16(al[mt][s], bh[nt], acc[mt][nt], 0, 0, 0);
                    acc[mt][nt] = __builtin_amdgcn_mfma_f32_16x16x32_bf16(ah[mt][s], bl[nt], acc[mt][nt], 0, 0, 0);
                }
        }

        // in-lane selection (codes ascending; strict < keeps lowest index)
#pragma unroll
        for (int nt = 0; nt < 4; ++nt) {
            const int code = cbase + nt * 16 + lr;
            const float wnv = wn_g[code];
#pragma unroll
            for (int mt = 0; mt < 2; ++mt)
#pragma unroll
                for (int j = 0; j < 4; ++j) {
                    const float sv = fmaf(-2.f, acc[mt][nt][j], wnv);
                    if (sv < b1[mt][j]) { b2[mt][j] = b1[mt][j]; b1[mt][j] = sv; i1[mt][j] = code; }
                    else if (sv < b2[mt][j]) b2[mt][j] = sv;
                }
        }
    }

    // ---- phase 1: (val,idx) butterfly for global best; keep local copies
    float g1[2][4]; int gi1[2][4];
#pragma unroll
    for (int mt = 0; mt < 2; ++mt)
#pragma unroll
        for (int j = 0; j < 4; ++j) { g1[mt][j] = b1[mt][j]; gi1[mt][j] = i1[mt][j]; }
#pragma unroll
    for (int m = 1; m < 16; m <<= 1) {
#pragma unroll
        for (int mt = 0; mt < 2; ++mt)
#pragma unroll
            for (int j = 0; j < 4; ++j) {
                const float ov = __shfl_xor(g1[mt][j], m, 64);
                const int   oi = __shfl_xor(gi1[mt][j], m, 64);
                if (ov < g1[mt][j] || (ov == g1[mt][j] && oi < gi1[mt][j])) {
                    g1[mt][j] = ov; gi1[mt][j] = oi;
                }
            }
    }
    // ---- phase 2: global 2nd-best = min over candidates excluding winner's slot
    float g2[2][4];
#pragma unroll
    for (int mt = 0; mt < 2; ++mt)
#pragma unroll
        for (int j = 0; j < 4; ++j)
            g2[mt][j] = (i1[mt][j] == gi1[mt][j]) ? b2[mt][j] : b1[mt][j];
#pragma unroll
    for (int m = 1; m < 16; m <<= 1) {
#pragma unroll
        for (int mt = 0; mt < 2; ++mt)
#pragma unroll
            for (int j = 0; j < 4; ++j)
                g2[mt][j] = fminf(g2[mt][j], __shfl_xor(g2[mt][j], m, 64));
    }

    if (lr == 0) {
#pragma unroll
        for (int mt = 0; mt < 2; ++mt)
#pragma unroll
            for (int j = 0; j < 4; ++j) {
                const int rl = wid * 32 + mt * 16 + g * 4 + j;
                ridx[rl] = gi1[mt][j];
                sb1[rl] = g1[mt][j];
                sb2[rl] = g2[mt][j];
            }
    }
    __syncthreads();

    // ---- winner verification (exact fp32) + gap test -> mark rows
    if (t < BM) {
        const float* xrow = x + (base + t) * 64;
        const int ci = ridx[t];
        const float* wrow = w + (long)ci * 64;
        float dot = 0.f;
#pragma unroll
        for (int p = 0; p < 16; ++p) {
            const float4 xv = *(const float4*)(xrow + p * 4);
            const float4 wv = *(const float4*)(wrow + p * 4);
            dot = fmaf(xv.x, wv.x, dot);
            dot = fmaf(xv.y, wv.y, dot);
            dot = fmaf(xv.z, wv.z, dot);
            dot = fmaf(xv.w, wv.w, dot);
        }
        const float sex = fmaf(-2.f, dot, wn_g[ci]);
        const bool unc = ((sb2[t] - sb1[t]) < TAU) || (fabsf(sex - sb1[t]) > CHK);
        if (unc) { const int p = atomicAdd(&nunc, 1); ulist[p] = t; }
    }
    __syncthreads();

    // ---- in-block exact fix: one wave per marked row
    const int nu = nunc;
    if (nu > 0) {
        for (int e = wid; e < nu; e += 4) {
            const int r = ulist[e];
            const float* xrow = x + (base + r) * 64;
            float bv = 3.4e38f; int bi = 0;
            for (int cc = 0; cc < 8; ++cc) {
                const int code = cc * 64 + l;
                const float* wrow = w + (long)code * 64;
                float dot = 0.f;
#pragma unroll
                for (int p = 0; p < 16; ++p) {
                    const float4 xv = *(const float4*)(xrow + p * 4);
                    const float4 wv = *(const float4*)(wrow + p * 4);
                    dot = fmaf(xv.x, wv.x, dot);
                    dot = fmaf(xv.y, wv.y, dot);
                    dot = fmaf(xv.z, wv.z, dot);
                    dot = fmaf(xv.w, wv.w, dot);
                }
                const float sv = fmaf(-2.f, dot, wn_g[code]);
                if (sv < bv) { bv = sv; bi = code; }
            }
#pragma unroll
            for (int m = 1; m < 64; m <<= 1) {
                const float ov = __shfl_xor(bv, m, 64);
                const int   oi = __shfl_xor(bi, m, 64);
                if (ov < bv || (ov == bv && oi < bi)) { bv = ov; bi = oi; }
            }
            if (l == 0) ridx[r] = bi;
        }
    }
    __syncthreads();

    // ---- epilogue: float4 gather -> q_sg, q; fused vq partials; fidx
    float* q_sg = out + 5;
    float* q    = out + 5 + (long)M_ * 64;
    float* fidx = out + 5 + 2L * M_ * 64;
    const int ry = t >> 4, dq = t & 15;
    float4 va = {0.f, 0.f, 0.f, 0.f}, vb = {0.f, 0.f, 0.f, 0.f};
#pragma unroll
    for (int i = 0; i < 8; ++i) {
        const int r = i * 16 + ry;
        const float4 wv = *(const float4*)(w + (long)ridx[r] * 64 + dq * 4);
        const float4 xv = *(const float4*)(x + (base + r) * 64 + dq * 4);
        const long off = (base + r) * 64 + dq * 4;
        *(float4*)(q_sg + off) = wv;
        *(float4*)(q + off) = wv;
        float4 p;
        p.x = (wv.x - xv.x) * (wv.x - xv.x);
        p.y = (wv.y - xv.y) * (wv.y - xv.y);
        p.z = (wv.z - xv.z) * (wv.z - xv.z);
        p.w = (wv.w - xv.w) * (wv.w - xv.w);
        if (i < 4) {
            va.x = fmaf(p.x, p.x, va.x); va.y = fmaf(p.y, p.y, va.y);
            va.z = fmaf(p.z, p.z, va.z); va.w = fmaf(p.w, p.w, va.w);
        } else {
            vb.x = fmaf(p.x, p.x, vb.x); vb.y = fmaf(p.y, p.y, vb.y);
            vb.z = fmaf(p.z, p.z, vb.z); vb.w = fmaf(p.w, p.w, vb.w);
        }
    }
    *(float4*)(red + ((0 * 16 + ry) * 16 + dq) * 4) = va;
    *(float4*)(red + ((1 * 16 + ry) * 16 + dq) * 4) = vb;
    if (t < BM) fidx[base + t] = (float)ridx[t];
    __syncthreads();
    if (t < 128) {
        const int n = t >> 6, dcol = t & 63;
        float s = 0.f;
#pragma unroll
        for (int u = 0; u < 16; ++u)
            s += red[((n * 16 + u) * 16 + (dcol >> 2)) * 4 + (dcol & 3)];
        float v = sqrtf(s);
#pragma unroll
        for (int m = 1; m < 64; m <<= 1) v += __shfl_xor(v, m, 64);
        if (dcol == 0) atomicAdd(ws + 0, v);
    }
}

// ---------------- k_final: orth from gram, rank via Gaussian elimination, losses
__global__ void k_final(const float* __restrict__ ws, float* __restrict__ out)
{
    __shared__ float g[64][65];
    __shared__ float osum[4];
    __shared__ float tol;
    const int t = threadIdx.x;
    float oacc = 0.f;
    for (int i = t; i < 4096; i += 256) {
        const int r = i >> 6, cl = i & 63;
        const float gv = ws[GRAM_OFF + i];
        g[r][cl] = gv;
        const float p = gv - (r == cl ? 1.f : 0.f);
        oacc = fmaf(p, p, oacc);
    }
#pragma unroll
    for (int m = 1; m < 64; m <<= 1) oacc += __shfl_xor(oacc, m, 64);
    if ((t & 63) == 0) osum[t >> 6] = oacc;
    __syncthreads();

    if (t == 0) {
        float maxd = 0.f;
        for (int i = 0; i < 64; ++i) maxd = fmaxf(maxd, fabsf(g[i][i]));
        tol = maxd * 1e-7f + 1e-30f;
    }
    __syncthreads();

    int rank = 0;
    const int j = t & 63, rq = t >> 6;
    for (int s = 0; s < 64; ++s) {
        const float p = g[s][s];
        const bool ok = fabsf(p) > tol;
        if (ok) {
            rank++;
            if (j > s) {
                const float rp = 1.f / p;
                const float gsj = g[s][j];
                for (int r = s + 1 + rq; r < 64; r += 4)
                    g[r][j] = fmaf(-(g[r][s] * rp), gsj, g[r][j]);
            }
        }
        __syncthreads();
    }

    if (t == 0) {
        const float vq = ws[0] / (float)(N_ * D_);
        const float orth = sqrtf(osum[0] + osum[1] + osum[2] + osum[3]);
        out[0] = 1.5f * vq;
        out[1] = vq;
        out[2] = vq;
        out[3] = orth;
        out[4] = (float)rank;
    }
}

// ---------------- launcher
extern "C" void kernel_launch(void* const* d_in, const int* in_sizes, int n_in,
                              void* d_out, int out_size, void* d_ws, size_t ws_size,
                              hipStream_t stream) {
    const float* x = (const float*)d_in[0];   // soft_fillers [N,R,D]
    const float* w = (const float*)d_in[1];   // weight [K,D]
    float* out = (float*)d_out;
    float* ws  = (float*)d_ws;
    const int pre = (ws_size >= (size_t)WS_NEED) ? 1 : 0;

    hipLaunchKernelGGL(k_pre, dim3(68), dim3(256), 0, stream, w, ws, pre);
    if (pre)
        hipLaunchKernelGGL((k_argmin<true>),  dim3(M_/BM), dim3(256), 0, stream, x, w, ws, out);
    else
        hipLaunchKernelGGL((k_argmin<false>), dim3(M_/BM), dim3(256), 0, stream, x, w, ws, out);
    hipLaunchKernelGGL(k_final, dim3(1), dim3(256), 0, stream, ws, out);
}

// Round 7
// 168.511 us; speedup vs baseline: 1.2787x; 1.2787x over previous
//
#include <hip/hip_runtime.h>
#include <math.h>

#define N_ 2048
#define R_ 64
#define D_ 64
#define K_ 512
#define M_ (N_*R_)      // 131072 rows
#define BM 128          // rows per argmin block (= 2 batch entries)
#define TAU 0.05f       // gap threshold (score units); approx err << TAU/2
#define CHK 0.02f       // winner exact-vs-approx verification threshold

// ws float offsets / byte layout:
// [0] vq acc | [16..527] wn | [1024..5119] gram |
// byte 32768: whi fragment-ordered (64KB) | byte 98304: wlo (64KB)
#define WN_OFF   16
#define GRAM_OFF 1024
#define WBF_BYTE 32768
#define WS_NEED  163840

typedef __attribute__((ext_vector_type(8))) short s16x8;
typedef __attribute__((ext_vector_type(4))) float f32x4;

static __device__ __forceinline__ unsigned short f2bf(float f) {
    unsigned u = __float_as_uint(f);
    u += 0x7FFFu + ((u >> 16) & 1u);
    return (unsigned short)(u >> 16);
}
static __device__ __forceinline__ float bf2f(unsigned short h) {
    return __uint_as_float(((unsigned)h) << 16);
}

// x-tile LDS addressing: row r (0..127), float4-granule q (0..15), XOR-swizzled
static __device__ __forceinline__ int xs_byte(int r, int q) {
    return r * 256 + (q >> 3) * 128 + (((q & 7) ^ (r & 7)) * 16);
}

// ---------------- k_pre: gram (b<64) | wn + zero acc (b 64-65) | W fragment-ordered split (b 66-67)
__global__ void k_pre(const float* __restrict__ w, float* __restrict__ ws, int pre) {
    const int b = blockIdx.x, t = threadIdx.x;
    if (b < 64) {
        __shared__ float red[4][64];
        const int i = b, j = t & 63, kg = t >> 6;
        float s = 0.f;
        for (int k = kg * 128; k < kg * 128 + 128; ++k)
            s = fmaf(w[k * 64 + i], w[k * 64 + j], s);
        red[kg][j] = s;
        __syncthreads();
        if (t < 64)
            ws[GRAM_OFF + i * 64 + t] = red[0][t] + red[1][t] + red[2][t] + red[3][t];
    } else if (b < 66) {
        const int code = (b - 64) * 256 + t;
        const float4* wr = (const float4*)(w + code * 64);
        float s = 0.f;
#pragma unroll
        for (int i = 0; i < 16; ++i) {
            float4 v = wr[i];
            s += v.x * v.x + v.y * v.y + v.z * v.z + v.w * v.w;
        }
        ws[WN_OFF + code] = s;
        if (b == 64 && t == 0) ws[0] = 0.f;
    } else {
        if (!pre) return;
        const int code = (b - 66) * 256 + t;   // 512 codes
        char* whi = (char*)ws + WBF_BYTE;
        char* wlo = whi + 65536;
        const int c = code >> 6, rr = code & 63;
        const int nt = rr >> 4, lr = rr & 15;
        for (int kg = 0; kg < 8; ++kg) {
            float4 v0 = *(const float4*)(w + code * 64 + kg * 8);
            float4 v1 = *(const float4*)(w + code * 64 + kg * 8 + 4);
            const float vv[8] = {v0.x, v0.y, v0.z, v0.w, v1.x, v1.y, v1.z, v1.w};
            s16x8 ph, pl;
#pragma unroll
            for (int j = 0; j < 8; ++j) {
                const unsigned short hb = f2bf(vv[j]);
                ph[j] = (short)hb;
                pl[j] = (short)f2bf(vv[j] - bf2f(hb));
            }
            const int s = kg >> 2, g = kg & 3, l = g * 16 + lr;
            const int off = (((c * 2 + s) * 4 + nt) << 10) + l * 16;  // FRAG(c,s,nt) + lane
            *(s16x8*)(whi + off) = ph;
            *(s16x8*)(wlo + off) = pl;
        }
    }
}

// ---------------- k_argmin: coalesced fragment loads, LDS x-tile, verified argmin
template<bool PRE>
__global__ __launch_bounds__(256, 4) void k_argmin(
    const float* __restrict__ x, const float* __restrict__ w,
    float* __restrict__ ws, float* __restrict__ out)
{
    __shared__ __align__(16) float xs[BM * 64];   // 32 KB swizzled x-tile; reused as red
    __shared__ float sb1[BM];
    __shared__ float sb2[BM];
    __shared__ int   ridx[BM];
    __shared__ int   ulist[BM];
    __shared__ int   nunc;

    const int t = threadIdx.x;
    const int l = t & 63, wid = t >> 6;
    const int g = l >> 4, lr = l & 15;
    const long base = (long)blockIdx.x * BM;
    const float* wn_g = ws + WN_OFF;
    const char* whi = (const char*)ws + WBF_BYTE;
    const char* wlo = whi + 65536;

    if (t == 0) nunc = 0;

    // ---- stage x-tile coalesced (wave reads 1KB runs), swizzled LDS dst
#pragma unroll
    for (int it = 0; it < 8; ++it) {
        const int idx = it * 256 + t;
        const int r = idx >> 4, q = idx & 15;
        const float4 v = *(const float4*)(x + (base + r) * 64 + q * 4);
        *(float4*)((char*)xs + xs_byte(r, q)) = v;
    }
    __syncthreads();

    // ---- A fragments from LDS, split to bf16 hi/lo in registers
    // row = lane%16 in tile, k = 32s + 8*(lane/16) + e
    s16x8 ah[2][2], al[2][2];
#pragma unroll
    for (int mt = 0; mt < 2; ++mt) {
        const int row = wid * 32 + mt * 16 + lr;
#pragma unroll
        for (int s = 0; s < 2; ++s) {
            const int kg = s * 4 + g;
            const float4 v0 = *(const float4*)((const char*)xs + xs_byte(row, kg * 2));
            const float4 v1 = *(const float4*)((const char*)xs + xs_byte(row, kg * 2 + 1));
            const float vv[8] = {v0.x, v0.y, v0.z, v0.w, v1.x, v1.y, v1.z, v1.w};
            s16x8 ph, pl;
#pragma unroll
            for (int j = 0; j < 8; ++j) {
                const unsigned short hb = f2bf(vv[j]);
                ph[j] = (short)hb;
                pl[j] = (short)f2bf(vv[j] - bf2f(hb));
            }
            ah[mt][s] = ph; al[mt][s] = pl;
        }
    }

    float b1[2][4], b2[2][4]; int i1[2][4];
#pragma unroll
    for (int mt = 0; mt < 2; ++mt)
#pragma unroll
        for (int j = 0; j < 4; ++j) { b1[mt][j] = 3.4e38f; b2[mt][j] = 3.4e38f; i1[mt][j] = 0; }

    for (int c = 0; c < 8; ++c) {
        const int cbase = c * 64;
        f32x4 acc[2][4];
        const f32x4 z = {0.f, 0.f, 0.f, 0.f};
#pragma unroll
        for (int mt = 0; mt < 2; ++mt)
#pragma unroll
            for (int nt = 0; nt < 4; ++nt) acc[mt][nt] = z;

#pragma unroll
        for (int s = 0; s < 2; ++s) {
            s16x8 bh[4], bl[4];
#pragma unroll
            for (int nt = 0; nt < 4; ++nt) {
                if constexpr (PRE) {
                    // fragment-ordered: wave reads contiguous 1KB
                    const int off = (((c * 2 + s) * 4 + nt) << 10) + l * 16;
                    bh[nt] = *(const s16x8*)(whi + off);
                    bl[nt] = *(const s16x8*)(wlo + off);
                } else {
                    const int crow = cbase + nt * 16 + lr;
                    const float* src = w + (long)crow * 64 + (s * 4 + g) * 8;
                    const float4 v0 = *(const float4*)src;
                    const float4 v1 = *(const float4*)(src + 4);
                    const float vv[8] = {v0.x, v0.y, v0.z, v0.w, v1.x, v1.y, v1.z, v1.w};
                    s16x8 ph, pl;
#pragma unroll
                    for (int j = 0; j < 8; ++j) {
                        const unsigned short hb = f2bf(vv[j]);
                        ph[j] = (short)hb;
                        pl[j] = (short)f2bf(vv[j] - bf2f(hb));
                    }
                    bh[nt] = ph; bl[nt] = pl;
                }
            }
#pragma unroll
            for (int nt = 0; nt < 4; ++nt)
#pragma unroll
                for (int mt = 0; mt < 2; ++mt) {
                    acc[mt][nt] = __builtin_amdgcn_mfma_f32_16x16x32_bf16(ah[mt][s], bh[nt], acc[mt][nt], 0, 0, 0);
                    acc[mt][nt] = __builtin_amdgcn_mfma_f32_16x16x32_bf16(al[mt][s], bh[nt], acc[mt][nt], 0, 0, 0);
                    acc[mt][nt] = __builtin_amdgcn_mfma_f32_16x16x32_bf16(ah[mt][s], bl[nt], acc[mt][nt], 0, 0, 0);
                }
        }

        // in-lane selection (codes ascending; strict < keeps lowest index)
#pragma unroll
        for (int nt = 0; nt < 4; ++nt) {
            const int code = cbase + nt * 16 + lr;
            const float wnv = wn_g[code];
#pragma unroll
            for (int mt = 0; mt < 2; ++mt)
#pragma unroll
                for (int j = 0; j < 4; ++j) {
                    const float sv = fmaf(-2.f, acc[mt][nt][j], wnv);
                    if (sv < b1[mt][j]) { b2[mt][j] = b1[mt][j]; b1[mt][j] = sv; i1[mt][j] = code; }
                    else if (sv < b2[mt][j]) b2[mt][j] = sv;
                }
        }
    }

    // ---- phase 1: (val,idx) butterfly for global best
    float g1[2][4]; int gi1[2][4];
#pragma unroll
    for (int mt = 0; mt < 2; ++mt)
#pragma unroll
        for (int j = 0; j < 4; ++j) { g1[mt][j] = b1[mt][j]; gi1[mt][j] = i1[mt][j]; }
#pragma unroll
    for (int m = 1; m < 16; m <<= 1) {
#pragma unroll
        for (int mt = 0; mt < 2; ++mt)
#pragma unroll
            for (int j = 0; j < 4; ++j) {
                const float ov = __shfl_xor(g1[mt][j], m, 64);
                const int   oi = __shfl_xor(gi1[mt][j], m, 64);
                if (ov < g1[mt][j] || (ov == g1[mt][j] && oi < gi1[mt][j])) {
                    g1[mt][j] = ov; gi1[mt][j] = oi;
                }
            }
    }
    // ---- phase 2: global 2nd-best excluding winner's slot
    float g2[2][4];
#pragma unroll
    for (int mt = 0; mt < 2; ++mt)
#pragma unroll
        for (int j = 0; j < 4; ++j)
            g2[mt][j] = (i1[mt][j] == gi1[mt][j]) ? b2[mt][j] : b1[mt][j];
#pragma unroll
    for (int m = 1; m < 16; m <<= 1) {
#pragma unroll
        for (int mt = 0; mt < 2; ++mt)
#pragma unroll
            for (int j = 0; j < 4; ++j)
                g2[mt][j] = fminf(g2[mt][j], __shfl_xor(g2[mt][j], m, 64));
    }

    if (lr == 0) {
#pragma unroll
        for (int mt = 0; mt < 2; ++mt)
#pragma unroll
            for (int j = 0; j < 4; ++j) {
                const int rl = wid * 32 + mt * 16 + g * 4 + j;
                ridx[rl] = gi1[mt][j];
                sb1[rl] = g1[mt][j];
                sb2[rl] = g2[mt][j];
            }
    }
    __syncthreads();

    // ---- winner verification (exact fp32; x from LDS, w row from L2)
    if (t < BM) {
        const int ci = ridx[t];
        const float* wrow = w + (long)ci * 64;
        float dot = 0.f;
#pragma unroll
        for (int p = 0; p < 16; ++p) {
            const float4 xv = *(const float4*)((const char*)xs + xs_byte(t, p));
            const float4 wv = *(const float4*)(wrow + p * 4);
            dot = fmaf(xv.x, wv.x, dot);
            dot = fmaf(xv.y, wv.y, dot);
            dot = fmaf(xv.z, wv.z, dot);
            dot = fmaf(xv.w, wv.w, dot);
        }
        const float sex = fmaf(-2.f, dot, wn_g[ci]);
        const bool unc = ((sb2[t] - sb1[t]) < TAU) || (fabsf(sex - sb1[t]) > CHK);
        if (unc) { const int p = atomicAdd(&nunc, 1); ulist[p] = t; }
    }
    __syncthreads();

    // ---- in-block exact fix: one wave per marked row (x via LDS broadcast)
    const int nu = nunc;
    if (nu > 0) {
        for (int e = wid; e < nu; e += 4) {
            const int r = ulist[e];
            float bv = 3.4e38f; int bi = 0;
            for (int cc = 0; cc < 8; ++cc) {
                const int code = cc * 64 + l;
                const float* wrow = w + (long)code * 64;
                float dot = 0.f;
#pragma unroll
                for (int p = 0; p < 16; ++p) {
                    const float4 xv = *(const float4*)((const char*)xs + xs_byte(r, p));
                    const float4 wv = *(const float4*)(wrow + p * 4);
                    dot = fmaf(xv.x, wv.x, dot);
                    dot = fmaf(xv.y, wv.y, dot);
                    dot = fmaf(xv.z, wv.z, dot);
                    dot = fmaf(xv.w, wv.w, dot);
                }
                const float sv = fmaf(-2.f, dot, wn_g[code]);
                if (sv < bv) { bv = sv; bi = code; }
            }
#pragma unroll
            for (int m = 1; m < 64; m <<= 1) {
                const float ov = __shfl_xor(bv, m, 64);
                const int   oi = __shfl_xor(bi, m, 64);
                if (ov < bv || (ov == bv && oi < bi)) { bv = ov; bi = oi; }
            }
            if (l == 0) ridx[r] = bi;
        }
    }
    __syncthreads();

    // ---- epilogue: gather w rows -> q_sg, q; vq partials (x from LDS)
    float* q_sg = out + 5;
    float* q    = out + 5 + (long)M_ * 64;
    float* fidx = out + 5 + 2L * M_ * 64;
    const int ry = t >> 4, dq = t & 15;
    float4 va = {0.f, 0.f, 0.f, 0.f}, vb = {0.f, 0.f, 0.f, 0.f};
#pragma unroll
    for (int i = 0; i < 8; ++i) {
        const int r = i * 16 + ry;
        const float4 wv = *(const float4*)(w + (long)ridx[r] * 64 + dq * 4);
        const float4 xv = *(const float4*)((const char*)xs + xs_byte(r, dq));
        const long off = (base + r) * 64 + dq * 4;
        *(float4*)(q_sg + off) = wv;
        *(float4*)(q + off) = wv;
        float4 p;
        p.x = (wv.x - xv.x) * (wv.x - xv.x);
        p.y = (wv.y - xv.y) * (wv.y - xv.y);
        p.z = (wv.z - xv.z) * (wv.z - xv.z);
        p.w = (wv.w - xv.w) * (wv.w - xv.w);
        if (i < 4) {
            va.x = fmaf(p.x, p.x, va.x); va.y = fmaf(p.y, p.y, va.y);
            va.z = fmaf(p.z, p.z, va.z); va.w = fmaf(p.w, p.w, va.w);
        } else {
            vb.x = fmaf(p.x, p.x, vb.x); vb.y = fmaf(p.y, p.y, vb.y);
            vb.z = fmaf(p.z, p.z, vb.z); vb.w = fmaf(p.w, p.w, vb.w);
        }
    }
    if (t < BM) fidx[base + t] = (float)ridx[t];
    __syncthreads();          // all LDS x reads done; reuse xs as red
    float* red = xs;
    *(float4*)(red + ((0 * 16 + ry) * 16 + dq) * 4) = va;
    *(float4*)(red + ((1 * 16 + ry) * 16 + dq) * 4) = vb;
    __syncthreads();
    if (t < 128) {
        const int n = t >> 6, dcol = t & 63;
        float s = 0.f;
#pragma unroll
        for (int u = 0; u < 16; ++u)
            s += red[((n * 16 + u) * 16 + (dcol >> 2)) * 4 + (dcol & 3)];
        float v = sqrtf(s);
#pragma unroll
        for (int m = 1; m < 64; m <<= 1) v += __shfl_xor(v, m, 64);
        if (dcol == 0) atomicAdd(ws + 0, v);
    }
}

// ---------------- k_final: orth from gram, rank via Gaussian elimination, losses
__global__ void k_final(const float* __restrict__ ws, float* __restrict__ out)
{
    __shared__ float g[64][65];
    __shared__ float osum[4];
    __shared__ float tol;
    const int t = threadIdx.x;
    float oacc = 0.f;
    for (int i = t; i < 4096; i += 256) {
        const int r = i >> 6, cl = i & 63;
        const float gv = ws[GRAM_OFF + i];
        g[r][cl] = gv;
        const float p = gv - (r == cl ? 1.f : 0.f);
        oacc = fmaf(p, p, oacc);
    }
#pragma unroll
    for (int m = 1; m < 64; m <<= 1) oacc += __shfl_xor(oacc, m, 64);
    if ((t & 63) == 0) osum[t >> 6] = oacc;
    __syncthreads();

    if (t == 0) {
        float maxd = 0.f;
        for (int i = 0; i < 64; ++i) maxd = fmaxf(maxd, fabsf(g[i][i]));
        tol = maxd * 1e-7f + 1e-30f;
    }
    __syncthreads();

    int rank = 0;
    const int j = t & 63, rq = t >> 6;
    for (int s = 0; s < 64; ++s) {
        const float p = g[s][s];
        const bool ok = fabsf(p) > tol;
        if (ok) {
            rank++;
            if (j > s) {
                const float rp = 1.f / p;
                const float gsj = g[s][j];
                for (int r = s + 1 + rq; r < 64; r += 4)
                    g[r][j] = fmaf(-(g[r][s] * rp), gsj, g[r][j]);
            }
        }
        __syncthreads();
    }

    if (t == 0) {
        const float vq = ws[0] / (float)(N_ * D_);
        const float orth = sqrtf(osum[0] + osum[1] + osum[2] + osum[3]);
        out[0] = 1.5f * vq;
        out[1] = vq;
        out[2] = vq;
        out[3] = orth;
        out[4] = (float)rank;
    }
}

// ---------------- launcher
extern "C" void kernel_launch(void* const* d_in, const int* in_sizes, int n_in,
                              void* d_out, int out_size, void* d_ws, size_t ws_size,
                              hipStream_t stream) {
    const float* x = (const float*)d_in[0];   // soft_fillers [N,R,D]
    const float* w = (const float*)d_in[1];   // weight [K,D]
    float* out = (float*)d_out;
    float* ws  = (float*)d_ws;
    const int pre = (ws_size >= (size_t)WS_NEED) ? 1 : 0;

    hipLaunchKernelGGL(k_pre, dim3(68), dim3(256), 0, stream, w, ws, pre);
    if (pre)
        hipLaunchKernelGGL((k_argmin<true>),  dim3(M_/BM), dim3(256), 0, stream, x, w, ws, out);
    else
        hipLaunchKernelGGL((k_argmin<false>), dim3(M_/BM), dim3(256), 0, stream, x, w, ws, out);
    hipLaunchKernelGGL(k_final, dim3(1), dim3(256), 0, stream, ws, out);
}